// Round 5
// baseline (3975.832 us; speedup 1.0000x reference)
//
#include <hip/hip_runtime.h>

typedef unsigned short u16;
typedef unsigned int u32;
typedef unsigned long long u64;
typedef __attribute__((ext_vector_type(8))) short bf16x8;
typedef __attribute__((ext_vector_type(4))) float f32x4;
typedef __attribute__((ext_vector_type(4))) unsigned short us4;

#define MFMA(a,b,c) __builtin_amdgcn_mfma_f32_16x16x32_bf16((a),(b),(c),0,0,0)

// B=128, SEQ=200, VOCAB=1400 (pad 1408), D=H=256, 4H=1024, NCLS=128, M=B*SEQ=25600

static __device__ __forceinline__ u16 f2b(float f){
  unsigned u = __float_as_uint(f);
  u += 0x7fffu + ((u >> 16) & 1u);          // RNE fp32 -> bf16
  return (u16)(u >> 16);
}
static __device__ __forceinline__ float sigm(float x){ return 1.0f/(1.0f+__expf(-x)); }
static __device__ __forceinline__ float tanhx(float x){
  x = fminf(fmaxf(x, -15.f), 15.f);
  float e = __expf(-2.f*x);
  return (1.f - e)/(1.f + e);
}
static __device__ __forceinline__ void gl16(const void* g, void* l){
  __builtin_amdgcn_global_load_lds((const __attribute__((address_space(1))) void*)g,
                                   (__attribute__((address_space(3))) void*)l, 16, 0, 0);
}

// ---------------- fused prep: inputs cvt + emb transpose-cvt + weights ----
__global__ __launch_bounds__(256) void k_prep(
  const float* __restrict__ in0, u16* __restrict__ A0,
  const float* __restrict__ emb, u16* __restrict__ embT,
  const float* __restrict__ s0, const float* __restrict__ s1, const float* __restrict__ s2,
  const float* __restrict__ s3, const float* __restrict__ s4, const float* __restrict__ s5,
  const float* __restrict__ s6,
  u16* __restrict__ d0, u16* __restrict__ d1, u16* __restrict__ d2, u16* __restrict__ d3,
  u16* __restrict__ d4, u16* __restrict__ d5, u16* __restrict__ d6)
{
  int bx = blockIdx.x, tid = threadIdx.x;
  if (bx < 35200){                     // inputs [25600 x 1400] -> bf16 padded 1408
    long long i4 = (long long)bx*256 + tid;      // < 9011200 exactly
    long long o = i4*4;
    int r = (int)(o / 1408);
    int c = (int)(o % 1408);
    us4 d;
    if (c + 4 <= 1400){
      f32x4 v = *(const f32x4*)&in0[(long long)r*1400 + c];
      d[0]=f2b(v[0]); d[1]=f2b(v[1]); d[2]=f2b(v[2]); d[3]=f2b(v[3]);
    } else {
      for (int k=0;k<4;k++){ int cc=c+k; d[k] = (cc<1400)? f2b(in0[(long long)r*1400+cc]) : (u16)0; }
    }
    *(us4*)&A0[(long long)r*1408 + c] = d;
  } else if (bx < 36608){              // emb [1400x256] -> embT [256x1408] bf16
    int idx = (bx-35200)*256 + tid;    // < 360448 exactly
    int n = idx / 1408, k = idx % 1408;
    embT[idx] = (k < 1400) ? f2b(emb[(long long)k*256 + n]) : (u16)0;
  } else {                             // 7 weight arrays fp32 -> bf16
    long long q = (long long)(bx-36608)*256 + tid;   // < 311296 exactly
    const float* src; u16* dst; long long rel;
    if      (q < 65536)  { src=s0; dst=d0; rel=q; }
    else if (q < 131072) { src=s1; dst=d1; rel=q-65536; }
    else if (q < 196608) { src=s2; dst=d2; rel=q-131072; }
    else if (q < 262144) { src=s3; dst=d3; rel=q-196608; }
    else if (q < 278528) { src=s4; dst=d4; rel=q-262144; }
    else if (q < 294912) { src=s5; dst=d5; rel=q-278528; }
    else                 { src=s6; dst=d6; rel=q-294912; }
    long long o = rel*4;
    f32x4 v = *(const f32x4*)&src[o];
    us4 d; d[0]=f2b(v[0]); d[1]=f2b(v[1]); d[2]=f2b(v[2]); d[3]=f2b(v[3]);
    *(us4*)&dst[o] = d;
  }
}

// ---------------- weight repack for streamed scan -------------------------
// wpk fragment id = (((lstm*4 + w)*8 + kk)*20 + tau)*64 + l  (16B each).
// tau 0..15: gate rows  (g=tau>>2, j = w*64 + (tau&3)*16 + lb)
// tau 16..19: Wd rows   (j = w*64 + (tau-16)*16 + lb)
// lane l: quad=l>>4 gives k-slice quad*8 within kk*32; lb=l&15 gives row.
// This matches the proven A-frag pattern Wall[row*256 + kk*32 + quad*8].
__global__ __launch_bounds__(256) void k_wpack(
  const u16* __restrict__ Wall1, const u16* __restrict__ Wd1,
  const u16* __restrict__ Wall2, const u16* __restrict__ Wd2,
  u16* __restrict__ wpk)
{
  int id = blockIdx.x*256 + threadIdx.x;   // 320*256 = 81920 exactly
  int l = id & 63, f = id >> 6;            // f 0..1279
  int tau = f % 20;
  int kk  = (f/20) & 7;
  int w   = (f/160) & 3;
  int lstm= f / 640;
  int quad = l >> 4, lb = l & 15;
  const u16* Wall = lstm ? Wall2 : Wall1;
  const u16* Wd   = lstm ? Wd2   : Wd1;
  const u16* src;
  if (tau < 16){
    int row = (tau>>2)*256 + w*64 + (tau&3)*16 + lb;
    src = &Wall[(long long)row*256 + kk*32 + quad*8];
  } else {
    int row = w*64 + (tau-16)*16 + lb;
    src = &Wd[(long long)row*256 + kk*32 + quad*8];
  }
  *(bf16x8*)&wpk[(long long)id*8] = *(const bf16x8*)src;
}

// ---------------- init: zero E + ctx (atomic accumulation targets) --------
__global__ __launch_bounds__(256) void k_init(float* __restrict__ E, float* __restrict__ ctx){
  int i = blockIdx.x*256 + threadIdx.x;     // 228*256 = 58368 exactly
  if (i < 25600) E[i] = 0.f;
  else ctx[i-25600] = 0.f;                  // 32768
}

// ---------------- bf16 MFMA GEMM: C[M,N] = A[M,K] * Bt[N,K]^T -------------
// EPI 1: write fp32 + bf16 copies
// EPI 4: dual-output ux GEMM, +bias pair, fp32 (blockIdx.y>=8 -> second set)
// EPI 5: ctx[b,col] += emb[row,col]*tanh(acc)*alpha[row]  (LDS + global atomics)
template<int EPI>
__global__ __launch_bounds__(256) void k_gemm(const u16* __restrict__ A, const u16* __restrict__ Bt,
    int N, int K,
    float* __restrict__ Cf, u16* __restrict__ Cb,
    const float* __restrict__ bias1, const float* __restrict__ bias2,
    const u16* __restrict__ Bt2, float* __restrict__ Cf2,
    const float* __restrict__ bias3, const float* __restrict__ bias4,
    const float* __restrict__ emb, const float* __restrict__ alpha)
{
  __shared__ __align__(16) u16 As[128*64];
  __shared__ __align__(16) u16 Bs[128*64];
  __shared__ float red[2][128];
  const int tid = threadIdx.x;
  const int l = tid & 63, w = tid >> 6;
  const int quad = l >> 4, lb = l & 15;
  const int wr = w >> 1, wc = w & 1;
  const long long m0 = (long long)blockIdx.x * 128;
  int n0 = blockIdx.y * 128;
  if (EPI==4 && blockIdx.y >= 8){
    Bt = Bt2; Cf = Cf2; bias1 = bias3; bias2 = bias4; n0 = (blockIdx.y-8)*128;
  }

  f32x4 acc[4][4];
  #pragma unroll
  for (int i=0;i<4;i++)
    #pragma unroll
    for (int j=0;j<4;j++) acc[i][j] = (f32x4){0.f,0.f,0.f,0.f};

  for (int kk = 0; kk < K; kk += 64){
    #pragma unroll
    for (int it=0; it<4; ++it){      // 128x64 bf16 tile, XOR-swizzled 16B slots
      int slot = it*256 + tid;
      int m = slot >> 3;
      int q = (slot & 7) ^ (m & 7);
      gl16(A + (m0+m)*K + kk + q*8, &As[slot*8]);
    }
    #pragma unroll
    for (int it=0; it<4; ++it){
      int slot = it*256 + tid;
      int m = slot >> 3;
      int q = (slot & 7) ^ (m & 7);
      gl16(Bt + (long long)(n0+m)*K + kk + q*8, &Bs[slot*8]);
    }
    __syncthreads();
    #pragma unroll
    for (int ks=0; ks<2; ++ks){
      int kq = quad + ks*4;
      bf16x8 af[4], bfr[4];
      #pragma unroll
      for (int i=0;i<4;i++){ int m = wr*64 + i*16 + lb; af[i]  = *(const bf16x8*)&As[m*64 + ((kq ^ (m&7))*8)]; }
      #pragma unroll
      for (int j=0;j<4;j++){ int n = wc*64 + j*16 + lb; bfr[j] = *(const bf16x8*)&Bs[n*64 + ((kq ^ (n&7))*8)]; }
      #pragma unroll
      for (int i=0;i<4;i++)
        #pragma unroll
        for (int j=0;j<4;j++)
          acc[i][j] = MFMA(af[i], bfr[j], acc[i][j]);
    }
    __syncthreads();
  }

  if (EPI==5){
    const int b0 = (int)(m0 / 200);
    red[tid>>7][tid&127] = 0.f;
    __syncthreads();
    #pragma unroll
    for (int i=0;i<4;i++){
      #pragma unroll
      for (int j=0;j<4;j++){
        int col = wc*64 + j*16 + lb;          // 0..127 within n0 tile
        #pragma unroll
        for (int r=0;r<4;r++){
          long long row = m0 + wr*64 + i*16 + quad*4 + r;
          long long o = row*N + n0 + col;
          float v = emb[o] * tanhx(acc[i][j][r]) * alpha[row];
          atomicAdd(&red[(int)(row/200) - b0][col], v);
        }
      }
    }
    __syncthreads();
    int bl = tid >> 7, col = tid & 127;       // 256 threads cover [2][128]
    int bb = b0 + bl;
    if (bb < 128) atomicAdd(&Cf[bb*256 + n0 + col], red[bl][col]);
    return;
  }

  #pragma unroll
  for (int i=0;i<4;i++){
    #pragma unroll
    for (int j=0;j<4;j++){
      int col = n0 + wc*64 + j*16 + lb;
      #pragma unroll
      for (int r=0;r<4;r++){
        long long row = m0 + wr*64 + i*16 + quad*4 + r;
        long long o = row*N + col;
        float v = acc[i][j][r];
        if (EPI==1){ Cf[o]=v; Cb[o]=f2b(v); }
        else { Cf[o] = v + bias1[col] + bias2[col]; }   // EPI 4
      }
    }
  }
}

// ---------------- TimeLSTM scan: batch-split, ZERO cross-WG sync ----------
// 16 WGs: lstm = bi&1, bc = bi>>1 (16 batches each). Each WG owns the FULL
// j=256 h/c state for its batches in LDS; nothing is exchanged between WGs.
// (bi&1 parity => the 2 WGs per XCD under round-robin share the same lstm's
// weights in that XCD's L2 — a locality heuristic only.)
//
// Weights are NOT register-resident: each wave streams its 160 packed
// fragments (20 row-tiles x 8 k-steps, 1KB each, fully coalesced from wpk)
// from L2 EVERY step. Wave w owns j in [w*64, w*64+64): 16 gate-row tiles
// (4 gates x 4 j-subtiles) + 4 Wd-row tiles. Per step:
//   1. issue ux (16 x f32x4) + ts loads     (consumed ~800cy later)
//   2. acc[0..15]=0, acc[16..19]=Wd bias
//   3. for kk in 0..7: hf,cf from LDS; 20 MFMA with streamed A-frags
//   4. elementwise (fp32 c in regs), E/out2 outputs
//   5. B1 raw s_barrier; write own h/c slice to LDS; lgkmcnt(0); B2
// Only intra-CU barriers — the MALL round-trip chain (7.3k cy/step in the
// j-split family) is gone entirely.
__global__ __launch_bounds__(256,1) void k_scan(
  const u16* __restrict__ wpk,
  const float* __restrict__ Wd1b, const float* __restrict__ ux1,
  const float* __restrict__ h01, const float* __restrict__ c01,
  const float* __restrict__ Wd2b, const float* __restrict__ ux2,
  const float* __restrict__ h02, const float* __restrict__ c02,
  const float* __restrict__ ts, const float* __restrict__ wa,
  float* __restrict__ E, u16* __restrict__ out2)
{
  __shared__ __align__(16) u16 hb[16][264];
  __shared__ __align__(16) u16 cb[16][264];
  const int bi = blockIdx.x;
  const int lstm = bi & 1;
  const int bc   = bi >> 1;            // 0..7
  const float* Wdb = lstm ? Wd2b : Wd1b;
  const float* ux  = lstm ? ux2  : ux1;
  const float* h0  = lstm ? h02  : h01;
  const float* c0  = lstm ? c02  : c01;

  const int tid = threadIdx.x;
  const int l = tid & 63, w = tid >> 6;
  const int quad = l >> 4, lb = l & 15;
  const int bg = bc*16 + lb;            // lane's batch (MFMA col)
  const int jb = w*64 + quad*4;         // lane's base j; tile jt adds jt*16

  const u16* wp = wpk + (long long)(lstm*4 + w)*81920 + l*8;  // this wave's frags

  // per-lane constants
  f32x4 bcs4[4], wav4[4], creg[4];
  #pragma unroll
  for (int jt=0; jt<4; ++jt){
    bcs4[jt] = *(const f32x4*)&Wdb[jb + jt*16];
    wav4[jt] = *(const f32x4*)&wa[jb + jt*16];
    creg[jt] = *(const f32x4*)&c0[(long long)bg*256 + jb + jt*16];
  }

  // init LDS h/c (16 batches x full 256 j), bf16
  {
    const int bbi = tid >> 4, j0i = (tid & 15) * 16;
    #pragma unroll
    for (int kq=0; kq<4; ++kq){
      f32x4 hv = *(const f32x4*)&h0[(long long)(bc*16+bbi)*256 + j0i + kq*4];
      f32x4 cv = *(const f32x4*)&c0[(long long)(bc*16+bbi)*256 + j0i + kq*4];
      us4 hp0, cp0;
      #pragma unroll
      for (int r=0;r<4;++r){ hp0[r]=f2b(hv[r]); cp0[r]=f2b(cv[r]); }
      *(us4*)&hb[bbi][j0i+kq*4] = hp0;
      *(us4*)&cb[bbi][j0i+kq*4] = cp0;
    }
  }
  __syncthreads();

  for (int s=0; s<200; ++s){
    // 1) ux + ts for this step (consumed after the GEMV)
    f32x4 uxv[16];
    #pragma unroll
    for (int g=0; g<4; ++g)
      #pragma unroll
      for (int jt=0; jt<4; ++jt)
        uxv[g*4+jt] = *(const f32x4*)&ux[((long long)bg*200 + s)*1024 + g*256 + jb + jt*16];
    float tcur = ts[(long long)bg*200 + s];

    // 2) acc init (gates zero — ux added at elementwise; Wd rows get bias)
    f32x4 acc[20];
    #pragma unroll
    for (int t=0; t<16; ++t) acc[t] = (f32x4){0.f,0.f,0.f,0.f};
    #pragma unroll
    for (int jt=0; jt<4; ++jt) acc[16+jt] = bcs4[jt];

    // 3) GEMV: 8 k-steps x 20 MFMA, weights streamed from L2 (coalesced 1KB)
    #pragma unroll
    for (int kk=0; kk<8; ++kk){
      bf16x8 hf = *(const bf16x8*)&hb[lb][kk*32 + quad*8];
      bf16x8 cf = *(const bf16x8*)&cb[lb][kk*32 + quad*8];
      const u16* wk = wp + kk*10240;
      #pragma unroll
      for (int t=0; t<16; ++t)
        acc[t] = MFMA(*(const bf16x8*)&wk[t*512], hf, acc[t]);
      #pragma unroll
      for (int jt=0; jt<4; ++jt)
        acc[16+jt] = MFMA(*(const bf16x8*)&wk[(16+jt)*512], cf, acc[16+jt]);
    }

    // 4) elementwise (fp32 c carried in regs)
    f32x4 hn4[4]; us4 hp4[4], cp4[4];
    #pragma unroll
    for (int jt=0; jt<4; ++jt){
      #pragma unroll
      for (int r=0; r<4; ++r){
        float cs1 = tanhx(acc[16+jt][r]);
        float cadj = creg[jt][r] + cs1*(tcur - 1.0f);
        float fg = sigm(acc[0*4+jt][r] + uxv[0*4+jt][r]);
        float ig = sigm(acc[1*4+jt][r] + uxv[1*4+jt][r]);
        float og = sigm(acc[2*4+jt][r] + uxv[2*4+jt][r]);
        float cg = sigm(acc[3*4+jt][r] + uxv[3*4+jt][r]);
        float cn = fg*cadj + ig*cg;
        float hv = og*tanhx(cn);
        creg[jt][r]=cn; hn4[jt][r]=hv;
        hp4[jt][r]=f2b(hv); cp4[jt][r]=f2b(cn);
      }
    }
    // outputs: lstm0 -> E partial (attention dot), lstm1 -> out2
    if (lstm==0){
      float e = 0.f;
      #pragma unroll
      for (int jt=0; jt<4; ++jt)
        #pragma unroll
        for (int r=0; r<4; ++r) e += hn4[jt][r]*wav4[jt][r];
      e += __shfl_xor(e, 16, 64);
      e += __shfl_xor(e, 32, 64);
      if (l < 16) atomicAdd(&E[(long long)bg*200 + s], e);
    } else {
      #pragma unroll
      for (int jt=0; jt<4; ++jt)
        *(us4*)&out2[((long long)bg*200 + s)*256 + jb + jt*16] = hp4[jt];
    }

    // 5) LDS h/c update (intra-CU only; raw barriers, no vmcnt drain)
    if (s < 199){
      asm volatile("" ::: "memory");
      __builtin_amdgcn_s_barrier();            // B1: all GEMV LDS reads done
      asm volatile("" ::: "memory");
      #pragma unroll
      for (int jt=0; jt<4; ++jt){
        *(us4*)&hb[lb][jb + jt*16] = hp4[jt];
        *(us4*)&cb[lb][jb + jt*16] = cp4[jt];
      }
      asm volatile("s_waitcnt lgkmcnt(0)" ::: "memory");
      __builtin_amdgcn_sched_barrier(0);
      __builtin_amdgcn_s_barrier();            // B2: h/c(s+1) visible
      asm volatile("" ::: "memory");
    }
  }
}

// ---------------- softmax over precomputed E -> alpha ----------------
__global__ __launch_bounds__(256) void k_attn(const float* __restrict__ E, float* __restrict__ alpha){
  __shared__ float buf[256];
  int b = blockIdx.x, tid = threadIdx.x;
  float Ev = (tid < 200) ? E[(long long)b*200 + tid] : -1e30f;
  buf[tid]=Ev; __syncthreads();
  for (int st=128; st>0; st>>=1){ if (tid<st) buf[tid]=fmaxf(buf[tid],buf[tid+st]); __syncthreads(); }
  float mx = buf[0]; __syncthreads();
  float e = (tid<200)? __expf(Ev-mx) : 0.f;
  buf[tid]=e; __syncthreads();
  for (int st=128; st>0; st>>=1){ if (tid<st) buf[tid]+=buf[tid+st]; __syncthreads(); }
  float sm = buf[0];
  if (tid<200) alpha[(long long)b*200+tid] = e/sm;
}

// ---------------- out = ctx @ Wout^T ----------------
__global__ __launch_bounds__(128) void k_out(const float* __restrict__ ctx, const float* __restrict__ Wout,
                                             float* __restrict__ out){
  __shared__ float cs[256];
  int b = blockIdx.x, t = threadIdx.x;
  cs[t] = ctx[b*256+t]; cs[t+128] = ctx[b*256+t+128];
  __syncthreads();
  const float* wr = Wout + (long long)t*256;
  float a0=0,a1=0,a2=0,a3=0;
  for (int j=0;j<256;j+=4){
    f32x4 v = *(const f32x4*)&wr[j];
    a0+=v[0]*cs[j]; a1+=v[1]*cs[j+1]; a2+=v[2]*cs[j+2]; a3+=v[3]*cs[j+3];
  }
  out[(long long)b*128 + t] = (a0+a1)+(a2+a3);
}

extern "C" void kernel_launch(void* const* d_in, const int* in_sizes, int n_in,
                              void* d_out, int out_size, void* d_ws, size_t ws_size,
                              hipStream_t stream)
{
  (void)in_sizes; (void)n_in; (void)out_size; (void)ws_size;
  const float* inputs = (const float*)d_in[0];
  const float* tstamp = (const float*)d_in[1];
  const float* emb    = (const float*)d_in[2];
  const float* Wall1w = (const float*)d_in[3];
  const float* Wall1b = (const float*)d_in[4];
  const float* Uall1w = (const float*)d_in[5];
  const float* Uall1b = (const float*)d_in[6];
  const float* Wd1w   = (const float*)d_in[7];
  const float* Wd1b   = (const float*)d_in[8];
  const float* Wall2w = (const float*)d_in[9];
  const float* Wall2b = (const float*)d_in[10];
  const float* Uall2w = (const float*)d_in[11];
  const float* Uall2b = (const float*)d_in[12];
  const float* Wd2w   = (const float*)d_in[13];
  const float* Wd2b   = (const float*)d_in[14];
  const float* wa     = (const float*)d_in[15];
  const float* Wbw    = (const float*)d_in[16];
  const float* Woutw  = (const float*)d_in[17];
  const float* h01    = (const float*)d_in[18];
  const float* c01    = (const float*)d_in[19];
  const float* h02    = (const float*)d_in[20];
  const float* c02    = (const float*)d_in[21];

  char* ws = (char*)d_ws;
  float* ux1   = (float*)(ws + 0);              // 104857600
  float* ux2   = (float*)(ws + 104857600LL);
  float* embF  = (float*)(ws + 209715200LL);    // 26214400
  u16*   embB  = (u16*)  (ws + 235929600LL);    // 13107200
  char*  scr   =          ws + 249036800LL;     // 72089600 region
  u16*   A0    = (u16*)scr;                     // 72089600 (dead after embed GEMM)
  u16*   out2  = (u16*)  (scr + 0);             // 13107200
  u16*   wpk   = (u16*)  (scr + 16777216LL);    // 1310720 (packed scan weights; inside dead A0 tail)
  float* alpha = (float*)(scr + 39321600LL);    // 102400
  float* ctx   = (float*)(scr + 39424000LL);    // 131072
  float* E     = (float*)(scr + 39555072LL);    // 102400
  u16* embT    = (u16*)(ws + 321126400LL);      // 720896
  u16* Wall1B  = (u16*)(ws + 321847296LL);      // 524288
  u16* Wall2B  = (u16*)(ws + 322371584LL);
  u16* Uall1B  = (u16*)(ws + 322895872LL);
  u16* Uall2B  = (u16*)(ws + 323420160LL);
  u16* Wd1B    = (u16*)(ws + 323944448LL);      // 131072
  u16* Wd2B    = (u16*)(ws + 324075520LL);
  u16* WbB     = (u16*)(ws + 324206592LL);
  // total ws: ~324.3 MB (same layout envelope as passing rounds)

  // 1) all conversions (inputs, emb^T, 7 weights) in one launch
  k_prep<<<37824, 256, 0, stream>>>(inputs, A0, emb, embT,
                                    Wall1w, Wall2w, Uall1w, Uall2w, Wd1w, Wd2w, Wbw,
                                    Wall1B, Wall2B, Uall1B, Uall2B, Wd1B, Wd2B, WbB);
  // 2) embedded = inputs @ emb  (fp32 + bf16 copies; consumes A0)
  k_gemm<1><<<dim3(200,2), 256, 0, stream>>>(A0, embT, 256, 1408, embF, embB,
                                             nullptr, nullptr, nullptr, nullptr,
                                             nullptr, nullptr, nullptr, nullptr);
  // 3) pack scan weights into coalesced fragment layout (A0 now dead)
  k_wpack<<<320, 256, 0, stream>>>(Wall1B, Wd1B, Wall2B, Wd2B, wpk);
  // 4) ux1,ux2 = embedded @ Uall{1,2}^T + (Uall_b + Wall_b), one launch
  k_gemm<4><<<dim3(200,16), 256, 0, stream>>>(embB, Uall1B, 1024, 256, ux1, nullptr,
                                              Uall1b, Wall1b,
                                              Uall2B, ux2, Uall2b, Wall2b,
                                              nullptr, nullptr);
  // 5) zero E + ctx (atomic accumulation targets)
  k_init<<<228, 256, 0, stream>>>(E, ctx);
  // 6) both TimeLSTM scans (16 WGs, batch-split, weights streamed from L2)
  k_scan<<<16, 256, 0, stream>>>(wpk,
                                 Wd1b, ux1, h01, c01,
                                 Wd2b, ux2, h02, c02,
                                 tstamp, wa, E, out2);
  // 7) alpha = softmax(E)
  k_attn<<<128, 256, 0, stream>>>(E, alpha);
  // 8) ctx += sum_s emb * tanh(out2 @ Wb^T) * alpha  (fused, no P buffer)
  k_gemm<5><<<dim3(200,2), 256, 0, stream>>>(out2, WbB, 256, 256, ctx, nullptr,
                                             nullptr, nullptr, nullptr, nullptr,
                                             nullptr, nullptr, embF, alpha);
  // 9) out = ctx @ Wout^T
  k_out<<<128, 128, 0, stream>>>(ctx, Woutw, (float*)d_out);
}